// Round 13
// baseline (50.508 us; speedup 1.0000x reference)
//
#include <hip/hip_runtime.h>

// Problem constants (fixed by setup_inputs)
#define K   19
#define C   256
#define HF  64
#define WF  128
#define HW  (HF * WF)
#define BB  4
#define HL  512
#define WL  1024

// f32 near-tie threshold: f32 distance error bound < ~1e-3 (32-FMA chains +
// 3-step butterfly); pixels whose top-2 f32 gap < TAU get an exact f64
// cooperative resolve over ALL k (proven resolver semantics, R10/R11).
#define TAU 0.015f

#define SLW  36            // padded words per channel-slice region (bank-disjoint)
#define KROW (8 * SLW)     // 288 words per k row

// Wave-autonomous: block = 256 thr = 4 independent waves; each wave owns 8
// pixels. lane = sl*8 + px8: px8 = pixel within group (consecutive lanes ->
// 32B-chunk coalesced feature loads), sl = channel slice (32 ch each).
// Per lane: acc[19] over its 32 channels (centroids from padded LDS,
// ds_read_b128 bank-conflict-free + broadcast); 3-step shfl_xor over sl gives
// every lane the full 19 dots of its pixel. No part[] exchange, no s_load
// chain in the hot loop, no inter-wave coupling after the staging barrier.
// 2048 blocks (~23 KB LDS -> 6-7 blocks/CU).
__global__ __launch_bounds__(256, 8) void centroid_mask_kernel(
    const float* __restrict__ feat0,   // feature_s2t
    const float* __restrict__ feat1,   // feature_target
    const float* __restrict__ cent0,   // centroids for map 0 (centroid_target)
    const float* __restrict__ cent1,   // centroids for map 1 (centroid_s2t)
    int* __restrict__ out)             // [2][BB][HL][WL] int32
{
    __shared__ __align__(16) float ctl[K * KROW];   // 21888 B padded centroids
    __shared__ double c2p[K][8];                     // exact ||c||^2 partials
    __shared__ float  sc2f[K];                       // rounded-exact ||c||^2

    const int map = blockIdx.y;
    const float* __restrict__ feat = (map == 0) ? feat0 : feat1;
    const float* __restrict__ cent = (map == 0) ? cent0 : cent1;

    const int tid  = threadIdx.x;
    const int lane = tid & 63;
    const int wv   = __builtin_amdgcn_readfirstlane(tid >> 6);  // 0..3, uniform
    const int px8  = lane & 7;     // pixel within this wave's group of 8
    const int sl   = lane >> 3;    // channel slice: channels [sl*32, sl*32+32)

    // ---- stage centroids into padded LDS + exact ||c||^2 (two cheap barriers) ----
    for (int idx = tid; idx < K * C; idx += 256) {
        const int k = idx >> 8, c = idx & (C - 1);
        ctl[k * KROW + (c >> 5) * SLW + (c & 31)] = cent[idx];
    }
    if (tid < K * 8) {
        const int k = tid >> 3, s8 = tid & 7;
        const float* cp = cent + k * C + s8 * 32;
        double s = 0.0;
        #pragma unroll
        for (int j = 0; j < 32; ++j) { double v = (double)cp[j]; s = fma(v, v, s); }
        c2p[k][s8] = s;
    }
    __syncthreads();
    if (tid < K) {
        double s = 0.0;
        #pragma unroll
        for (int j = 0; j < 8; ++j) s += c2p[tid][j];
        sc2f[tid] = (float)s;
    }
    __syncthreads();
    // ---- from here on, waves are fully independent ----

    const int p  = (blockIdx.x * 4 + wv) * 8 + px8;   // pixel 0..32767
    const int hw = p & (HW - 1);
    const int b  = p >> 13;

    const float* __restrict__ fp = feat + (size_t)b * C * HW + hw;
    const int cb = sl * 32;        // this lane's channel base

    float acc[K];
    #pragma unroll
    for (int k = 0; k < K; ++k) acc[k] = 0.f;

    #pragma unroll
    for (int ch = 0; ch < 4; ++ch) {          // 4 chunks of 8 channels
        float f8[8];
        #pragma unroll
        for (int i = 0; i < 8; ++i)
            f8[i] = fp[(size_t)(cb + ch * 8 + i) * HW];
        const int wbase = sl * SLW + ch * 8;
        #pragma unroll
        for (int k = 0; k < K; ++k) {
            const float4 cA = *(const float4*)&ctl[k * KROW + wbase];
            const float4 cB = *(const float4*)&ctl[k * KROW + wbase + 4];
            float a = acc[k];
            a = fmaf(f8[0], cA.x, a); a = fmaf(f8[1], cA.y, a);
            a = fmaf(f8[2], cA.z, a); a = fmaf(f8[3], cA.w, a);
            a = fmaf(f8[4], cB.x, a); a = fmaf(f8[5], cB.y, a);
            a = fmaf(f8[6], cB.z, a); a = fmaf(f8[7], cB.w, a);
            acc[k] = a;
        }
    }

    // reduce partial dots over sl (lane bits 3..5): every lane gets full dots
    #pragma unroll
    for (int k = 0; k < K; ++k) {
        float a = acc[k];
        a += __shfl_xor(a, 8, 64);
        a += __shfl_xor(a, 16, 64);
        a += __shfl_xor(a, 32, 64);
        acc[k] = a;
    }

    // distances + in-lane argmin (ascending k, strict < = first-min) + flag
    float d[K];
    #pragma unroll
    for (int k = 0; k < K; ++k) d[k] = sc2f[k] - 2.0f * acc[k];
    int best = 0; float dm = d[0];
    #pragma unroll
    for (int k = 1; k < K; ++k) if (d[k] < dm) { dm = d[k]; best = k; }
    int cnt = 0;
    #pragma unroll
    for (int k = 0; k < K; ++k) cnt += (int)(d[k] - dm < TAU);

    // ---- per-wave cooperative exact-f64 resolve of flagged pixels ----
    // d (hence cnt) is replicated across the 8 sl-lanes of a pixel; ballot on
    // sl==0 puts flagged-pixel bits at lanes 0..7 (= px8).
    unsigned long long ball = __ballot((cnt >= 2) && (sl == 0));
    while (ball) {
        const int fpx = (int)__builtin_ctzll(ball);   // flagged px8, 0..7
        ball &= ball - 1;
        const int pp  = (blockIdx.x * 4 + wv) * 8 + fpx;
        const int phw = pp & (HW - 1);
        const int pb  = pp >> 13;
        const float* __restrict__ fcol = feat + (size_t)pb * C * HW + phw;

        const int c0 = lane << 2;                     // channels 4l..4l+3
        double pf[4];
        #pragma unroll
        for (int q = 0; q < 4; ++q)
            pf[q] = (double)fcol[(size_t)(c0 + q) * HW];

        double bd = 1e300; int bi = 0;
        for (int k = 0; k < K; ++k) {                 // full k: exact argmin
            const float4 cc = *(const float4*)(cent + (size_t)k * C + c0);
            double s = 0.0, t;
            t = pf[0] - (double)cc.x; s = fma(t, t, s);
            t = pf[1] - (double)cc.y; s = fma(t, t, s);
            t = pf[2] - (double)cc.z; s = fma(t, t, s);
            t = pf[3] - (double)cc.w; s = fma(t, t, s);
            #pragma unroll
            for (int off = 1; off < 64; off <<= 1) s += __shfl_xor(s, off, 64);
            if (s < bd) { bd = s; bi = k; }           // strict <, ascending k
        }
        if (px8 == fpx) best = bi;                    // all 8 sl-lanes adopt
    }

    // write row sl of this pixel's 8x8 upsampled block
    // (lanes px8=0..7 of one sl -> 256 B contiguous per store pair)
    const int w = hw & (WF - 1);
    const int h = hw >> 7;
    int4 v = make_int4(best, best, best, best);
    int* __restrict__ ob = out + (size_t)map * (BB * HL * WL)
                               + (size_t)b * (HL * WL)
                               + (size_t)(h * 8 + sl) * WL + (size_t)(w * 8);
    *(int4*)(ob)     = v;
    *(int4*)(ob + 4) = v;
}

extern "C" void kernel_launch(void* const* d_in, const int* in_sizes, int n_in,
                              void* d_out, int out_size, void* d_ws, size_t ws_size,
                              hipStream_t stream) {
    const float* feature_s2t     = (const float*)d_in[0];
    const float* feature_target  = (const float*)d_in[1];
    // d_in[2], d_in[3]: labels — only shapes matter, unused
    const float* centroid_s2t    = (const float*)d_in[4];
    const float* centroid_target = (const float*)d_in[5];
    int* out = (int*)d_out;

    // 32 px per block (4 waves x 8 px) -> grid (1024, 2) = 2048 blocks
    dim3 grid(32768 / 32, 2);
    dim3 block(256);
    hipLaunchKernelGGL(centroid_mask_kernel, grid, block, 0, stream,
                       feature_s2t, feature_target,
                       centroid_target, centroid_s2t, out);
}

// Round 14
// 48.012 us; speedup vs baseline: 1.0520x; 1.0520x over previous
//
#include <hip/hip_runtime.h>

// Problem constants (fixed by setup_inputs)
#define K   19
#define C   256
#define HF  64
#define WF  128
#define HW  (HF * WF)
#define BB  4
#define HL  512
#define WL  1024

// f32 near-tie threshold: f32 distance error bound < ~1e-3; pixels whose
// top-2 f32 gap < TAU get an exact f64 cooperative resolve (same wave).
#define TAU 0.015f

typedef const __attribute__((address_space(1))) void* gas1_t;
typedef __attribute__((address_space(3))) void*       las3_t;

// Block = 256 thr = 4 waves, 32-px tile. KEY CHANGE vs R4-R13: features are
// staged global->LDS with __builtin_amdgcn_global_load_lds (async DMA, no
// destination VGPRs) -- 32 instrs per wave ALL in flight, which the compiler
// cannot remat/shorten (the R4-R12 profiles showed VGPR_Count=36: the f[32]
// "preload" never lived in registers, so per-wave load queue depth was ~4 and
// effective HBM ran at 0.9-1.9 TB/s vs the 6.7 TB/s the harness fill kernels
// achieve). Compute is c-outer from LDS: f consumed immediately (nothing to
// remat), centroids from an LDS [c][20] table (2-address reads = free).
__global__ __launch_bounds__(256, 2) void centroid_mask_kernel(
    const float* __restrict__ feat0,   // feature_s2t
    const float* __restrict__ feat1,   // feature_target
    const float* __restrict__ cent0,   // centroids for map 0 (centroid_target)
    const float* __restrict__ cent1,   // centroids for map 1 (centroid_s2t)
    int* __restrict__ out)             // [2][BB][HL][WL] int32
{
    __shared__ __align__(16) float fl[C * 32];    // [c][px] feature tile, 32 KB
    __shared__ __align__(16) float ct[C * 20];    // [c][k] centroids, 20.5 KB
    __shared__ float  part[4][K][32];             // per-wave partial dots, 9.7 KB
    __shared__ double c2p[K][8];                  // exact ||c||^2 partials
    __shared__ float  sc2f[K];                    // rounded-exact ||c||^2

    const int map = blockIdx.y;
    const float* __restrict__ feat = (map == 0) ? feat0 : feat1;
    const float* __restrict__ cent = (map == 0) ? cent0 : cent1;

    const int tid  = threadIdx.x;
    const int lane = tid & 63;
    const int wv   = __builtin_amdgcn_readfirstlane(tid >> 6);  // 0..3, uniform
    const int px   = lane & 31;    // pixel within tile
    const int hs   = lane >> 5;    // half-slice select (0/1)

    const int p0  = blockIdx.x * 32;        // tile base pixel (one h-row segment)
    const int hw0 = p0 & (HW - 1);
    const int b   = p0 >> 13;

    // ---- async-stage feature tile: wave wv stages channels [wv*64, wv*64+64) ----
    // one instr = 2 channels x 32 px = 256 B; 32 instrs/wave, all in flight.
    {
        const float* __restrict__ fb = feat + (size_t)b * C * HW + hw0;
        #pragma unroll
        for (int i = 0; i < 32; ++i) {
            const int cpair = wv * 64 + 2 * i;
            const float* g = fb + (size_t)(cpair + hs) * HW + px;   // per-lane src
            __builtin_amdgcn_global_load_lds((gas1_t)g,
                                             (las3_t)&fl[cpair * 32], 4, 0, 0);
        }
    }

    // ---- stage centroid table [c][20] + exact ||c||^2 partials (overlaps DMA) ----
    for (int i = tid; i < K * C; i += 256) {
        const int k = i >> 8, c = i & (C - 1);
        ct[c * 20 + k] = cent[i];
    }
    if (tid < K * 8) {
        const int k = tid >> 3, s8 = tid & 7;
        const float* cp = cent + k * C + s8 * 32;
        double s = 0.0;
        #pragma unroll
        for (int j = 0; j < 32; ++j) { double v = (double)cp[j]; s = fma(v, v, s); }
        c2p[k][s8] = s;
    }
    __syncthreads();   // drains vmcnt(0): feature tile + ct ready

    if (tid < K) {
        double s = 0.0;
        #pragma unroll
        for (int j = 0; j < 8; ++j) s += c2p[tid][j];
        sc2f[tid] = (float)s;
    }

    // ---- main: c-outer from LDS; lane covers channels [cb, cb+32) of pixel px ----
    const int cb = wv * 64 + hs * 32;
    float acc[K];
    #pragma unroll
    for (int k = 0; k < K; ++k) acc[k] = 0.f;

    #pragma unroll 4
    for (int cc = 0; cc < 32; ++cc) {
        const int c = cb + cc;
        const float f = fl[c * 32 + px];                       // 2-way = free
        const float4* __restrict__ cq = (const float4*)&ct[c * 20];
        const float4 q0 = cq[0], q1 = cq[1], q2 = cq[2], q3 = cq[3], q4 = cq[4];
        acc[ 0] = fmaf(f, q0.x, acc[ 0]); acc[ 1] = fmaf(f, q0.y, acc[ 1]);
        acc[ 2] = fmaf(f, q0.z, acc[ 2]); acc[ 3] = fmaf(f, q0.w, acc[ 3]);
        acc[ 4] = fmaf(f, q1.x, acc[ 4]); acc[ 5] = fmaf(f, q1.y, acc[ 5]);
        acc[ 6] = fmaf(f, q1.z, acc[ 6]); acc[ 7] = fmaf(f, q1.w, acc[ 7]);
        acc[ 8] = fmaf(f, q2.x, acc[ 8]); acc[ 9] = fmaf(f, q2.y, acc[ 9]);
        acc[10] = fmaf(f, q2.z, acc[10]); acc[11] = fmaf(f, q2.w, acc[11]);
        acc[12] = fmaf(f, q3.x, acc[12]); acc[13] = fmaf(f, q3.y, acc[13]);
        acc[14] = fmaf(f, q3.z, acc[14]); acc[15] = fmaf(f, q3.w, acc[15]);
        acc[16] = fmaf(f, q4.x, acc[16]); acc[17] = fmaf(f, q4.y, acc[17]);
        acc[18] = fmaf(f, q4.z, acc[18]);
    }

    // merge the two half-slices (lane bit 5), then write per-wave partials
    #pragma unroll
    for (int k = 0; k < K; ++k) acc[k] += __shfl_xor(acc[k], 32, 64);
    if (lane < 32) {
        #pragma unroll
        for (int k = 0; k < K; ++k) part[wv][k][px] = acc[k];
    }
    __syncthreads();

    // ---- epilogue: wave 0 only (R8/R12 lesson: single-wave epilogue wins) ----
    if (wv == 0) {
        float d[K];
        #pragma unroll
        for (int k = 0; k < K; ++k) {
            const float s = ((part[0][k][px] + part[1][k][px])
                           + (part[2][k][px] + part[3][k][px]));
            d[k] = sc2f[k] - 2.0f * s;
        }
        int best = 0; float dm = d[0];
        #pragma unroll
        for (int k = 1; k < K; ++k) if (d[k] < dm) { dm = d[k]; best = k; }
        int cnt = 0;
        #pragma unroll
        for (int k = 0; k < K; ++k) cnt += (int)(d[k] - dm < TAU);

        // per-wave cooperative exact-f64 resolve of flagged pixels (proven)
        unsigned long long ball = __ballot((cnt >= 2) && (lane < 32));
        while (ball) {
            const int fpx = (int)__builtin_ctzll(ball);   // flagged px, 0..31
            ball &= ball - 1;
            const int phw = hw0 + fpx;
            const float* __restrict__ fcol = feat + (size_t)b * C * HW + phw;

            const int c0 = lane << 2;                     // channels 4l..4l+3
            double pf[4];
            #pragma unroll
            for (int q = 0; q < 4; ++q)
                pf[q] = (double)fcol[(size_t)(c0 + q) * HW];

            double bd = 1e300; int bi = 0;
            for (int k = 0; k < K; ++k) {                 // full k: exact argmin
                const float4 cc2 = *(const float4*)(cent + (size_t)k * C + c0);
                double s = 0.0, t;
                t = pf[0] - (double)cc2.x; s = fma(t, t, s);
                t = pf[1] - (double)cc2.y; s = fma(t, t, s);
                t = pf[2] - (double)cc2.z; s = fma(t, t, s);
                t = pf[3] - (double)cc2.w; s = fma(t, t, s);
                #pragma unroll
                for (int off = 1; off < 64; off <<= 1) s += __shfl_xor(s, off, 64);
                if (s < bd) { bd = s; bi = k; }           // strict <, ascending k
            }
            if (px == fpx) best = bi;                     // both halves adopt
        }

        // write the 8x8 upsampled block (lanes 0-31 only; 1 KB contiguous/row)
        if (lane < 32) {
            const int phw = hw0 + px;
            const int w = phw & (WF - 1);
            const int h = phw >> 7;
            int4 v = make_int4(best, best, best, best);
            int* __restrict__ ob = out + (size_t)map * (BB * HL * WL)
                                       + (size_t)b * (HL * WL)
                                       + (size_t)(h * 8) * WL + (size_t)(w * 8);
            #pragma unroll
            for (int r = 0; r < 8; ++r) {
                *(int4*)(ob + (size_t)r * WL)     = v;
                *(int4*)(ob + (size_t)r * WL + 4) = v;
            }
        }
    }
}

extern "C" void kernel_launch(void* const* d_in, const int* in_sizes, int n_in,
                              void* d_out, int out_size, void* d_ws, size_t ws_size,
                              hipStream_t stream) {
    const float* feature_s2t     = (const float*)d_in[0];
    const float* feature_target  = (const float*)d_in[1];
    // d_in[2], d_in[3]: labels — only shapes matter, unused
    const float* centroid_s2t    = (const float*)d_in[4];
    const float* centroid_target = (const float*)d_in[5];
    int* out = (int*)d_out;

    // 32 px per block -> grid (1024, 2) = 2048 blocks, 2 resident/CU
    dim3 grid(32768 / 32, 2);
    dim3 block(256);
    hipLaunchKernelGGL(centroid_mask_kernel, grid, block, 0, stream,
                       feature_s2t, feature_target,
                       centroid_target, centroid_s2t, out);
}

// Round 15
// 25.381 us; speedup vs baseline: 1.9900x; 1.8917x over previous
//
#include <hip/hip_runtime.h>

// Problem constants (fixed by setup_inputs)
#define K   19
#define C   256
#define HF  64
#define WF  128
#define HW  (HF * WF)
#define BB  4
#define HL  512
#define WL  1024

// f32 near-tie threshold: f32 distance error bound < ~1e-3; pixels whose
// top-2 f32 gap < TAU get an exact f64 cooperative resolve (same wave).
#define TAU 0.015f

// Block = 256 thr = 4 waves, tile = 64 px (lane = pixel). Wave wv owns
// channels [wv*64, wv*64+64) -- wave-uniform, so centroids stay SGPR operands.
// KEY CHANGE vs R8: chunk-outer / k-inner with persistent acc[19]. Each
// feature value is loaded ONCE into f8[] registers and consumed 19x from
// registers. R8's k-outer loop needed f[32] live (didn't fit at VGPR=36), so
// the compiler rematerialized the loads inside every k iteration: ~608 VMEM
// instrs/wave (19x re-read through L1) ~= 16us of per-CU texture-pipe
// serialization -- the measured 26.5us vs the ~10us floor. Here the k-loop
// reads registers only; loads cannot be sunk. LDS drops to ~21KB -> 7
// blocks/CU (28 waves/CU of TLP to cover the per-chunk load latency).
__global__ __launch_bounds__(256, 4) void centroid_mask_kernel(
    const float* __restrict__ feat0,   // feature_s2t
    const float* __restrict__ feat1,   // feature_target
    const float* __restrict__ cent0,   // centroids for map 0 (centroid_target)
    const float* __restrict__ cent1,   // centroids for map 1 (centroid_s2t)
    int* __restrict__ out)             // [2][BB][HL][WL] int32
{
    __shared__ float  part[4 * K * 64];  // [wv][k][px], px stride 1: conflict-free
    __shared__ double c2p[K][8];         // exact ||c||^2 partials
    __shared__ double sc2d[K];           // exact ||c||^2 (f64)
    __shared__ float  sc2f[K];           // rounded-exact ||c||^2 (f32)

    const int map = blockIdx.y;
    const float* __restrict__ feat = (map == 0) ? feat0 : feat1;
    const float* __restrict__ cent = (map == 0) ? cent0 : cent1;

    const int tid  = threadIdx.x;
    const int lane = tid & 63;
    const int wv   = __builtin_amdgcn_readfirstlane(tid >> 6);   // 0..3, uniform

    // exact ||c_k||^2 partials (f64), 152 threads, overlaps with main
    if (tid < K * 8) {
        const int k = tid >> 3, sl = tid & 7;
        const float* cp = cent + k * C + sl * 32;
        double s = 0.0;
        #pragma unroll
        for (int j = 0; j < 32; ++j) { double v = (double)cp[j]; s = fma(v, v, s); }
        c2p[k][sl] = s;
    }

    const int p  = blockIdx.x * 64 + lane;     // pixel in [0, 32768)
    const int hw = p & (HW - 1);
    const int b  = p >> 13;
    const int cb = wv * 64;

    const float* __restrict__ fp = feat + (size_t)b * C * HW + (size_t)cb * HW + hw;
    const float* __restrict__ cw = cent + cb;            // + k*C + ch (uniform)

    float acc[K];
    #pragma unroll
    for (int k = 0; k < K; ++k) acc[k] = 0.f;

    // 8 chunks of 8 channels: load f8 once (8 independent coalesced loads,
    // batch-issued), then 19x8 FMAs from REGISTERS with SGPR centroid operand.
    #pragma unroll
    for (int ch = 0; ch < 8; ++ch) {
        float f8[8];
        #pragma unroll
        for (int i = 0; i < 8; ++i)
            f8[i] = fp[(size_t)(ch * 8 + i) * HW];
        #pragma unroll
        for (int k = 0; k < K; ++k) {
            const float* __restrict__ ck = cw + (size_t)k * C + ch * 8;
            float a = acc[k];
            a = fmaf(f8[0], ck[0], a); a = fmaf(f8[1], ck[1], a);
            a = fmaf(f8[2], ck[2], a); a = fmaf(f8[3], ck[3], a);
            a = fmaf(f8[4], ck[4], a); a = fmaf(f8[5], ck[5], a);
            a = fmaf(f8[6], ck[6], a); a = fmaf(f8[7], ck[7], a);
            acc[k] = a;
        }
    }

    // write this wave's full-64-channel partial dots (lane-contiguous)
    float* __restrict__ pw = &part[(wv * K) * 64 + lane];
    #pragma unroll
    for (int k = 0; k < K; ++k) pw[k * 64] = acc[k];
    __syncthreads();

    if (tid < K) {
        double s = 0.0;
        #pragma unroll
        for (int j = 0; j < 8; ++j) s += c2p[tid][j];
        sc2d[tid] = s;
        sc2f[tid] = (float)s;
    }
    __syncthreads();

    // ---- epilogue: wave 0, lane = pixel (R8 verbatim, 4-way part sum) ----
    if (tid < 64) {
        const int pix = tid;
        float d[K];
        #pragma unroll
        for (int k = 0; k < K; ++k) {
            const float s = (part[(0 * K + k) * 64 + pix] + part[(1 * K + k) * 64 + pix])
                          + (part[(2 * K + k) * 64 + pix] + part[(3 * K + k) * 64 + pix]);
            d[k] = sc2f[k] - 2.0f * s;
        }
        int best = 0; float m1 = d[0];
        #pragma unroll
        for (int k = 1; k < K; ++k) if (d[k] < m1) { m1 = d[k]; best = k; }

        // near-tie candidates within TAU of the f32 min (always includes best)
        unsigned cmask = 0u;
        #pragma unroll
        for (int k = 0; k < K; ++k) if (d[k] - m1 < TAU) cmask |= (1u << k);

        // cooperative exact-f64 resolve of flagged pixels (proven, R8)
        const bool need = (cmask & (cmask - 1)) != 0u;
        unsigned long long ball = __ballot(need);
        while (ball) {
            const int px = (int)__builtin_ctzll(ball);   // lowest flagged lane
            ball &= ball - 1;
            const unsigned pm  = __shfl(cmask, px, 64);
            const int      phw = __shfl(hw,    px, 64);
            const int      pb  = __shfl(b,     px, 64);
            const float* __restrict__ fcol = feat + (size_t)pb * C * HW + phw;

            const int c0 = tid << 2;                     // channels 4l..4l+3
            double pf[4];
            #pragma unroll
            for (int j = 0; j < 4; ++j)
                pf[j] = (double)fcol[(size_t)(c0 + j) * HW];

            double bd = 1e300; int bi = 0;
            unsigned mm = pm;
            while (mm) {                      // ascending k, strict < tie-break
                const int k = (int)__builtin_ctz(mm);
                mm &= mm - 1;
                const float* __restrict__ ck = cent + (size_t)k * C + c0;
                double s = 0.0;
                #pragma unroll
                for (int j = 0; j < 4; ++j)
                    s = fma(pf[j], (double)ck[j], s);
                #pragma unroll
                for (int off = 1; off < 64; off <<= 1)
                    s += __shfl_xor(s, off, 64);
                const double dk = sc2d[k] - 2.0 * s;
                if (dk < bd) { bd = dk; bi = k; }
            }
            if (tid == px) best = bi;         // all lanes agree on bi
        }

        // write the 8x8 nearest-upsampled block
        const int w = hw & (WF - 1);
        const int h = hw >> 7;
        int4 v = make_int4(best, best, best, best);
        int* __restrict__ ob = out + (size_t)map * (BB * HL * WL)
                                   + (size_t)b * (HL * WL)
                                   + (size_t)(h * 8) * WL + (size_t)(w * 8);
        #pragma unroll
        for (int r = 0; r < 8; ++r) {
            *(int4*)(ob + (size_t)r * WL)     = v;
            *(int4*)(ob + (size_t)r * WL + 4) = v;
        }
    }
}

extern "C" void kernel_launch(void* const* d_in, const int* in_sizes, int n_in,
                              void* d_out, int out_size, void* d_ws, size_t ws_size,
                              hipStream_t stream) {
    const float* feature_s2t     = (const float*)d_in[0];
    const float* feature_target  = (const float*)d_in[1];
    // d_in[2], d_in[3]: labels — only shapes matter, unused
    const float* centroid_s2t    = (const float*)d_in[4];
    const float* centroid_target = (const float*)d_in[5];
    int* out = (int*)d_out;

    dim3 grid(32768 / 64, 2);   // (512, 2) -> 1024 blocks, up to 7/CU resident
    dim3 block(256);
    hipLaunchKernelGGL(centroid_mask_kernel, grid, block, 0, stream,
                       feature_s2t, feature_target,
                       centroid_target, centroid_s2t, out);
}